// Round 1
// 417.086 us; speedup vs baseline: 1.2341x; 1.2341x over previous
//
#include <hip/hip_runtime.h>

// ScannedRNN (GRU w/ reset masking) T=1024,B=128,H=256 — stream-packed
// segment-parallel scan, v5: gi_gemm rebuilt as m97-structure f16 GEMM.
//
//   conv_a: ins f32 -> f16 once (memory-bound, ~35us).
//   gi_gemm: 128x128 tile, BK=32, A/B both f16 staged via
//     global_load_lds dwordx4 (linear LDS, 2 barriers/K-step, 8 K-steps).
//     Old version was latency-bound at 265us (MfmaUtil 7.8%): f32 loads +
//     scalar cvt + 8B LDS writes. New floor ~60-80us.
//   E1 transpose resets; E2 per-row extract; E3 len-suffix-scan; E4 scatter
//   -> length-sorted segs. str_mark: closed-form preex -> stream marks.
//   scan_stream: unchanged (Wh resident in 192 VGPRs, 3 barriers/iter).
//
// Column permutation: c' = 48*(u>>4) + g*16 + (u&15), g in {r,z,n}. Wave w
// owns c' [96w,96w+96) = u in [32w,32w+32) with complete gate triples.

typedef _Float16 half2_t __attribute__((ext_vector_type(2)));
typedef _Float16 half4_t __attribute__((ext_vector_type(4)));
typedef _Float16 half8_t __attribute__((ext_vector_type(8)));
typedef float f32x4 __attribute__((ext_vector_type(4)));

#define T_DIM 1024
#define B_DIM 128
#define H_DIM 256
#define N3 768
#define NSTREAM 4096    // 256 blocks x 16 rows
#define ROWS 16

__device__ __forceinline__ int perm_n(int cp) {
  int ublk = cp / 48;
  int rem = cp % 48;
  int g = rem >> 4;
  int u4 = rem & 15;
  return g * 256 + ublk * 16 + u4;
}

// ---------------- prepack ----------------

__global__ void prep_whb(const float* __restrict__ Wh, unsigned* __restrict__ WhB) {
  int i = blockIdx.x * 256 + threadIdx.x;   // 0..98303 (dword = 2 halves)
  int h = 2 * i;
  int idx = h & 7;
  int lane = (h >> 3) & 63;
  int ntk = h >> 9;
  int nt = ntk % 48;
  int kt = ntk / 48;
  int k = kt * 32 + ((lane >> 4) * 8) + idx;
  int n = perm_n(nt * 16 + (lane & 15));
  half2_t p;
  p.x = (_Float16)Wh[(size_t)k * N3 + n];
  p.y = (_Float16)Wh[(size_t)(k + 1) * N3 + n];
  WhB[i] = __builtin_bit_cast(unsigned, p);
}

__global__ void prep_witp(const float* __restrict__ Wi, _Float16* __restrict__ WiTp) {
  int i = blockIdx.x * 256 + threadIdx.x;   // 0..196607
  int cp = i >> 8;
  int k = i & 255;
  WiTp[(size_t)cp * 256 + k] = (_Float16)Wi[(size_t)k * N3 + perm_n(cp)];
}

__global__ void prep_bip(const float* __restrict__ bi, float* __restrict__ bip) {
  int i = threadIdx.x;
  bip[i] = bi[perm_n(i)];
}

__global__ void init_h(const float* __restrict__ h0, float* __restrict__ h_state) {
  int i = blockIdx.x * 256 + threadIdx.x;
  h_state[i] = h0[i];
}

// ins f32 -> f16 (chunk slice), vectorized 32B-read/16B-write per thread-iter
__global__ __launch_bounds__(256) void conv_a(
    const float* __restrict__ src, _Float16* __restrict__ dst, int n8) {
  int i = blockIdx.x * 256 + threadIdx.x;
  const int stride = gridDim.x * 256;
  for (; i < n8; i += stride) {
    float4 a = ((const float4*)src)[2 * i];
    float4 b = ((const float4*)src)[2 * i + 1];
    half8_t h;
    h[0] = (_Float16)a.x; h[1] = (_Float16)a.y;
    h[2] = (_Float16)a.z; h[3] = (_Float16)a.w;
    h[4] = (_Float16)b.x; h[5] = (_Float16)b.y;
    h[6] = (_Float16)b.z; h[7] = (_Float16)b.w;
    ((half8_t*)dst)[i] = h;
  }
}

// ---------------- segment extraction ----------------

__global__ void seg_transpose(const int* __restrict__ resets, int* __restrict__ resT) {
  int i = blockIdx.x * 256 + threadIdx.x;   // 0..131071
  int b = i >> 10;
  int t = i & 1023;
  resT[i] = resets[(size_t)t * B_DIM + b];
}

// rec: start(10) | len(11)<<10 | rankInRowLen(10)<<21 | carry(1)<<31
__global__ __launch_bounds__(256) void seg_extract(
    const int* __restrict__ resT, int t0, int steps,
    unsigned* __restrict__ rowsegs, unsigned* __restrict__ rowcnt,
    unsigned* __restrict__ lhist) {
  const int b = blockIdx.x;
  const int tid = threadIdx.x;
  const int lane = tid & 63;
  const int w = tid >> 6;
  const int per = (steps + 255) >> 8;

  __shared__ unsigned short sstartL[1025];
  __shared__ unsigned lcur[1025];
  __shared__ unsigned wsum[4];

  for (int l = tid; l <= steps; l += 256) lcur[l] = 0;

  const int* rrow = resT + (size_t)b * T_DIM + t0;
  int myfirst = tid * per;
  unsigned cnt = 0;
  for (int i = 0; i < per; ++i) {
    int s = myfirst + i;
    if (s < steps && (s == 0 || rrow[s] != 0)) cnt++;
  }
  unsigned pre = cnt;
#pragma unroll
  for (int off = 1; off < 64; off <<= 1) {
    unsigned v = __shfl_up(pre, off);
    if (lane >= off) pre += v;
  }
  if (lane == 63) wsum[w] = pre;
  __syncthreads();
  unsigned wbase = 0, total = 0;
#pragma unroll
  for (int i = 0; i < 4; ++i) {
    if (i < w) wbase += wsum[i];
    total += wsum[i];
  }
  unsigned r = wbase + pre - cnt;
  for (int i = 0; i < per; ++i) {
    int s = myfirst + i;
    if (s < steps && (s == 0 || rrow[s] != 0)) sstartL[r++] = (unsigned short)s;
  }
  if (tid == 0) { sstartL[total] = (unsigned short)steps; rowcnt[b] = total; }
  __syncthreads();

  const unsigned carry0 = (rrow[0] == 0) ? 1u : 0u;
  for (unsigned rr = tid; rr < total; rr += 256) {
    int st = sstartL[rr];
    int len = (int)sstartL[rr + 1] - st;
    unsigned carry = (st == 0) ? carry0 : 0u;
    unsigned rk = atomicAdd(&lcur[len], 1u);   // LDS; placement-only
    rowsegs[(size_t)b * T_DIM + rr] =
        (unsigned)st | ((unsigned)len << 10) | (rk << 21) | (carry << 31);
  }
  __syncthreads();
  for (int l = tid; l <= steps; l += 256) lhist[(size_t)l * 128 + b] = lcur[l];
}

// cursors[len] = #segs with len' > len; Warr[len] = work of len' > len; nseg.
__global__ __launch_bounds__(1024) void seg_prefix2(
    const unsigned* __restrict__ lhist, unsigned* __restrict__ rowoff,
    unsigned* __restrict__ cursors, unsigned* __restrict__ Warr,
    unsigned* __restrict__ nseg, int steps) {
  __shared__ unsigned cs[1024];
  __shared__ unsigned cs2[1024];
  const int tid = threadIdx.x;
  const int len = tid + 1;
  unsigned run = 0;
  if (len <= steps) {
    for (int b = 0; b < 128; ++b) {
      rowoff[(size_t)len * 128 + b] = run;
      run += lhist[(size_t)len * 128 + b];
    }
  }
  unsigned own = run;
  unsigned own2 = run * (unsigned)len;
  cs[tid] = own;
  cs2[tid] = own2;
  for (int off = 1; off < 1024; off <<= 1) {
    __syncthreads();
    unsigned v = (tid + off < 1024) ? cs[tid + off] : 0u;
    unsigned v2 = (tid + off < 1024) ? cs2[tid + off] : 0u;
    __syncthreads();
    cs[tid] += v;
    cs2[tid] += v2;
  }
  cursors[len] = cs[tid] - own;
  Warr[len] = cs2[tid] - own2;
  if (tid == 0) *nseg = cs[0];
}

// segs: start(10) | len(11)<<10 | b(7)<<21 | carry(1)<<28  (length-sorted desc)
__global__ void seg_scatter2(
    const unsigned* __restrict__ rowsegs, const unsigned* __restrict__ rowcnt,
    const unsigned* __restrict__ rowoff, const unsigned* __restrict__ cursors,
    unsigned* __restrict__ segs) {
  int i = blockIdx.x * 256 + threadIdx.x;
  int b = i >> 10;
  int rr = i & 1023;
  if ((unsigned)rr >= rowcnt[b]) return;
  unsigned rec = rowsegs[i];
  unsigned st = rec & 0x3FF;
  unsigned len = (rec >> 10) & 0x7FF;
  unsigned rk = (rec >> 21) & 0x3FF;
  unsigned carry = rec >> 31;
  unsigned dst = cursors[len] + rowoff[(size_t)len * 128 + b] + rk;
  segs[dst] = st | (len << 10) | ((unsigned)b << 21) | (carry << 28);
}

// Stream boundary marks via closed-form preex. sstart/preexS pre-memset 0xFF.
__global__ void str_mark(
    const unsigned* __restrict__ segs, const unsigned* __restrict__ nseg_p,
    const unsigned* __restrict__ cursors, const unsigned* __restrict__ Warr,
    unsigned* __restrict__ sstart, unsigned* __restrict__ preexS, int Q) {
  unsigned r = blockIdx.x * 256 + threadIdx.x;
  unsigned n = *nseg_p;
  if (r >= n) return;
  unsigned rec = segs[r];
  unsigned len = (rec >> 10) & 0x7FF;
  unsigned pre = Warr[len] + len * (r - cursors[len]);
  unsigned st = pre / (unsigned)Q;
  unsigned stp;
  if (r == 0) {
    sstart[0] = 0; preexS[0] = 0; stp = 0;
  } else {
    unsigned rec2 = segs[r - 1];
    unsigned len2 = (rec2 >> 10) & 0x7FF;
    unsigned pre2 = Warr[len2] + len2 * (r - 1 - cursors[len2]);
    stp = pre2 / (unsigned)Q;
  }
  for (unsigned s = stp + 1; s <= st; ++s) { sstart[s] = r; preexS[s] = pre; }
}

// ---------------- phase 1: gi GEMM (m97 structure, f16 in / f16 out) ----------------
// A16: [M][256] f16 (pre-converted ins). BT: WiTp [768][256] f16.
// 128x128 tile, BK=32, global_load_lds dwordx4 staging, linear LDS
// (16 KB -> ~8 blocks/CU). 4 waves: wr=w>>1, wc=w&1, 4x4 16x16 frags each.
__global__ __launch_bounds__(256) void gi_gemm(
    const _Float16* __restrict__ A16,
    const _Float16* __restrict__ BT,
    const float* __restrict__ bip,
    _Float16* __restrict__ Cout,
    int M) {
  __shared__ _Float16 Al[128 * 32];
  __shared__ _Float16 Bl[128 * 32];
  const int tid = threadIdx.x;
  const int lane = tid & 63;
  const int w = tid >> 6;
  const int wr = w >> 1, wc = w & 1;
  const int m0 = blockIdx.y * 128;
  const int n0 = blockIdx.x * 128;

  // staging: each gload_lds = 64 lanes x 16B = 16 rows x 64B (one BK-slab row
  // chunk). LDS dest is wave-uniform base + lane*16 (linear); source per-lane.
  const int srow = lane >> 2;     // row within 16-row group
  const int schunk = lane & 3;    // 16B chunk within row

  f32x4 acc[4][4] = {};

  for (int ks = 0; ks < 256; ks += 32) {
#pragma unroll
    for (int rr = 0; rr < 2; ++rr) {
      const int row = w * 32 + rr * 16;   // wave-uniform
      __builtin_amdgcn_global_load_lds(
          (const __attribute__((address_space(1))) void*)
              ((const char*)A16 + ((size_t)(m0 + row + srow) * 256 + ks) * 2 + schunk * 16),
          (__attribute__((address_space(3))) void*)((char*)Al + row * 64),
          16, 0, 0);
      __builtin_amdgcn_global_load_lds(
          (const __attribute__((address_space(1))) void*)
              ((const char*)BT + ((size_t)(n0 + row + srow) * 256 + ks) * 2 + schunk * 16),
          (__attribute__((address_space(3))) void*)((char*)Bl + row * 64),
          16, 0, 0);
    }
    __syncthreads();   // drains vmcnt: tiles ready

    half8_t af[4], bf[4];
#pragma unroll
    for (int m = 0; m < 4; ++m)
      af[m] = *(const half8_t*)&Al[(size_t)(wr * 64 + m * 16 + (lane & 15)) * 32 + (lane >> 4) * 8];
#pragma unroll
    for (int n = 0; n < 4; ++n)
      bf[n] = *(const half8_t*)&Bl[(size_t)(wc * 64 + n * 16 + (lane & 15)) * 32 + (lane >> 4) * 8];
#pragma unroll
    for (int m = 0; m < 4; ++m)
#pragma unroll
      for (int n = 0; n < 4; ++n)
        acc[m][n] = __builtin_amdgcn_mfma_f32_16x16x32_f16(af[m], bf[n], acc[m][n], 0, 0, 0);
    __syncthreads();   // frag reads done before next stage overwrites
  }

#pragma unroll
  for (int m = 0; m < 4; ++m) {
    int row = m0 + wr * 64 + m * 16 + (lane >> 4) * 4;
#pragma unroll
    for (int n = 0; n < 4; ++n) {
      int col = n0 + wc * 64 + n * 16 + (lane & 15);
      float bv = bip[col];
#pragma unroll
      for (int r2 = 0; r2 < 4; ++r2)
        Cout[(size_t)(row + r2) * N3 + col] = (_Float16)(acc[m][n][r2] + bv);
    }
  }
}

// ---------------- phase 2: stream-packed scan, Wh in VGPRs ----------------
// rst[row]: t(10) | b(7)<<10 | rem(11)<<17 | carry(1)<<28
__global__ __launch_bounds__(512)
__attribute__((amdgpu_waves_per_eu(1, 2)))
void scan_stream(
    const _Float16* __restrict__ WhB,
    const _Float16* __restrict__ gi,
    const unsigned* __restrict__ segs,
    const unsigned* __restrict__ sstart,
    const unsigned* __restrict__ preexS,
    const unsigned* __restrict__ nseg_ptr,
    const float* __restrict__ bhn,
    const float* __restrict__ h_in,
    float* __restrict__ h_out,
    float* __restrict__ ys,
    float* __restrict__ hfin,
    int t0, int steps, int Q) {
  __shared__ _Float16 h_lds[ROWS][264];   // 8.4 KB
  __shared__ _Float16 giL[ROWS][776];     // 24.8 KB
  __shared__ unsigned rst[ROWS];
  __shared__ unsigned rowrank[ROWS];
  __shared__ unsigned rowpw[ROWS];
  __shared__ unsigned rfresh[ROWS];
  __shared__ unsigned wava[8];

  const int tid = threadIdx.x;
  const int lane = tid & 63;
  const int w = tid >> 6;
  const int sbase = blockIdx.x * ROWS;
  const unsigned nseg = *nseg_ptr;

  // ---- row init from stream marks ----
  if (tid < ROWS) {
    const unsigned st = sbase + tid;
    unsigned r = sstart[st], pw = preexS[st];
    unsigned v = 0u, rk = 0xFFFFFFFFu, rpw = 0u;
    if (r < nseg && pw < (st + 1) * (unsigned)Q) {
      unsigned rec = segs[r];
      unsigned len = (rec >> 10) & 0x7FF;
      v = (rec & 0x3FF) | (((rec >> 21) & 0x7F) << 10) | (len << 17) |
          (((rec >> 28) & 1u) << 28);
      rk = r; rpw = pw + len;
    }
    rst[tid] = v; rowrank[tid] = rk; rowpw[tid] = rpw; rfresh[tid] = 0;
  }
  if (tid < 8) wava[tid] = 1u;

  // ---- resident Wh: 48 B-fragments (192 VGPR), loaded once ----
  half8_t whr[48];
#pragma unroll
  for (int kt = 0; kt < 8; ++kt)
#pragma unroll
    for (int q = 0; q < 6; ++q)
      whr[kt * 6 + q] =
          *(const half8_t*)&WhB[(((size_t)kt * 48 + w * 6 + q) * 64 + lane) * 8];

  __syncthreads();
  // initial h: wave w owns rows 2w, 2w+1; lane covers u = lane*4..+3
#pragma unroll
  for (int rr = 0; rr < 2; ++rr) {
    int row = 2 * w + rr;
    unsigned s = rst[row];
    float4 o = make_float4(0.f, 0.f, 0.f, 0.f);
    if (s & (1u << 28))
      o = *(const float4*)&h_in[(size_t)((s >> 10) & 0x7F) * 256 + lane * 4];
    half4_t hv;
    hv.x = (_Float16)o.x; hv.y = (_Float16)o.y;
    hv.z = (_Float16)o.z; hv.w = (_Float16)o.w;
    *(half4_t*)&h_lds[row][lane * 4] = hv;
  }

  const int r16 = lane & 15;
  const int q4 = (lane >> 4) * 4;
  const int kq8 = (lane >> 4) * 8;
  const int u0 = w * 32 + r16;
  const float bh0 = bhn[u0];
  const float bh1 = bhn[u0 + 16];

  while (true) {
    __syncthreads();   // (C) h_lds/state/wava stable
    unsigned alive = 0;
#pragma unroll
    for (int i = 0; i < 8; ++i) alive += wava[i];
    if (!alive) break;

    // ---- gi DMA for this step: rows 2w, 2w+1 (wave-uniform) ----
#pragma unroll
    for (int rr = 0; rr < 2; ++rr) {
      const int row = 2 * w + rr;
      const unsigned ss = rst[row];
      if ((ss >> 17) & 0x7FF) {
        const char* src = (const char*)(gi +
            ((size_t)(ss & 0x3FF) * B_DIM + ((ss >> 10) & 0x7F)) * N3);
        char* dst = (char*)&giL[row][0];
#if __has_builtin(__builtin_amdgcn_global_load_lds)
        __builtin_amdgcn_global_load_lds(
            (const __attribute__((address_space(1))) void*)(src + (size_t)lane * 16),
            (__attribute__((address_space(3))) void*)dst, 16, 0, 0);
        __builtin_amdgcn_global_load_lds(
            (const __attribute__((address_space(1))) void*)(src + 1024 + (size_t)lane * 4),
            (__attribute__((address_space(3))) void*)(dst + 1024), 4, 0, 0);
        __builtin_amdgcn_global_load_lds(
            (const __attribute__((address_space(1))) void*)(src + 1280 + (size_t)lane * 4),
            (__attribute__((address_space(3))) void*)(dst + 1280), 4, 0, 0);
#else
        {
          uint4 a = *(const uint4*)(src + ((size_t)(lane & 31)) * 48);
          uint4 b = *(const uint4*)(src + ((size_t)(lane & 31)) * 48 + 16);
          uint4 c = *(const uint4*)(src + ((size_t)(lane & 31)) * 48 + 32);
          if ((lane >> 5) == 0) {
            char* d2 = dst + ((size_t)(lane & 31)) * 48;
            *(uint4*)(d2) = a; *(uint4*)(d2 + 16) = b; *(uint4*)(d2 + 32) = c;
          }
        }
#endif
      }
    }

    // ---- MFMA: gh(16 rows) = h @ Wh, B entirely from registers ----
    f32x4 acc[6] = {};
#pragma unroll
    for (int kt = 0; kt < 8; ++kt) {
      half8_t afr = *(const half8_t*)&h_lds[r16][kt * 32 + kq8];
#pragma unroll
      for (int q = 0; q < 6; ++q)
        acc[q] = __builtin_amdgcn_mfma_f32_16x16x32_f16(afr, whr[kt * 6 + q], acc[q], 0, 0, 0);
    }
    __syncthreads();   // (G) drains vmcnt: giL ready; h_lds reads done

    // ---- gates (write h_lds in place) ----
#pragma unroll
    for (int j = 0; j < 2; ++j) {
      const int u = u0 + j * 16;
      const int cb = w * 96 + j * 48 + r16;
      const float bh = j ? bh1 : bh0;
#pragma unroll
      for (int e = 0; e < 4; ++e) {
        const int row = q4 + e;
        if ((rst[row] >> 17) & 0x7FF) {
          const float gr = (float)giL[row][cb];
          const float gz = (float)giL[row][cb + 16];
          const float gn = (float)giL[row][cb + 32];
          const float sigr = 1.f / (1.f + __expf(-(gr + acc[3 * j][e])));
          const float sigz = 1.f / (1.f + __expf(-(gz + acc[3 * j + 1][e])));
          const float narg = gn + sigr * (acc[3 * j + 2][e] + bh);
          const float eo = __expf(-2.f * narg);
          const float nn = 2.f / (1.f + eo) - 1.f;
          const float hold = (float)h_lds[row][u];
          const float hnew = (1.f - sigz) * nn + sigz * hold;
          h_lds[row][u] = (_Float16)hnew;
        }
      }
    }
    __syncthreads();   // (G2) gates done

    // ---- output + state roll + fresh h init: all wave-local (rows 2w,2w+1) ----
    unsigned alv = 0;
#pragma unroll
    for (int rr = 0; rr < 2; ++rr) {
      const int row = 2 * w + rr;
      const unsigned sp = rst[row];
      const unsigned rem = (sp >> 17) & 0x7FF;
      if (rem) {
        const int t = sp & 0x3FF;
        const int b = (sp >> 10) & 0x7F;
        half4_t hv = *(const half4_t*)&h_lds[row][lane * 4];
        float4 o;
        o.x = (float)hv.x; o.y = (float)hv.y; o.z = (float)hv.z; o.w = (float)hv.w;
        *(float4*)&ys[(((size_t)(t0 + t) * B_DIM + b) * H_DIM) + lane * 4] = o;
        if (rem == 1) {
          if (t == steps - 1) *(float4*)&h_out[(size_t)b * 256 + lane * 4] = o;
          if (t0 + t == T_DIM - 1) *(float4*)&hfin[(size_t)b * 256 + lane * 4] = o;
        }
        if (lane == 0) {
          rfresh[row] = 0u;
          if (rem > 1) {
            rst[row] = (unsigned)(t + 1) | ((unsigned)b << 10) | ((rem - 1) << 17);
            alv++;
          } else {
            unsigned ns = 0u;
            const unsigned st = sbase + row;
            unsigned rn = rowrank[row] + 1, pw = rowpw[row];
            if (rn < nseg && pw < (st + 1) * (unsigned)Q) {
              unsigned rec = segs[rn];
              unsigned len = (rec >> 10) & 0x7FF;
              ns = (rec & 0x3FF) | (((rec >> 21) & 0x7F) << 10) | (len << 17) |
                   (((rec >> 28) & 1u) << 28);
              rowrank[row] = rn; rowpw[row] = pw + len;
              rfresh[row] = 1u;
              alv++;
            }
            rst[row] = ns;
          }
        }
      }
    }
    if (lane == 0) wava[w] = alv;
    // fresh-roll h init (same wave wrote rfresh/rst -> intra-wave visible)
#pragma unroll
    for (int rr = 0; rr < 2; ++rr) {
      const int row = 2 * w + rr;
      if (rfresh[row]) {
        unsigned s = rst[row];
        float4 o = make_float4(0.f, 0.f, 0.f, 0.f);
        if (s & (1u << 28))
          o = *(const float4*)&h_in[(size_t)((s >> 10) & 0x7F) * 256 + lane * 4];
        half4_t hv;
        hv.x = (_Float16)o.x; hv.y = (_Float16)o.y;
        hv.z = (_Float16)o.z; hv.w = (_Float16)o.w;
        *(half4_t*)&h_lds[row][lane * 4] = hv;
      }
    }
  }
}

// ---------------- launch ----------------
extern "C" void kernel_launch(void* const* d_in, const int* in_sizes, int n_in,
                              void* d_out, int out_size, void* d_ws, size_t ws_size,
                              hipStream_t stream) {
  const float* ins    = (const float*)d_in[0];
  const int*   resets = (const int*)d_in[1];
  const float* h0     = (const float*)d_in[2];
  const float* Wi     = (const float*)d_in[3];
  const float* Wh     = (const float*)d_in[4];
  const float* bi     = (const float*)d_in[5];
  const float* bhn    = (const float*)d_in[6];
  float* out  = (float*)d_out;
  float* hfin = out;
  float* ys   = out + B_DIM * H_DIM;

  char* ws = (char*)d_ws;
  unsigned*  WhB     = (unsigned*)(ws + 0);            //  393216
  _Float16*  WiTp    = (_Float16*)(ws + 393216);       //  393216 -> 786432
  float*     bip     = (float*)(ws + 786432);          //    3072 -> 789504
  float*     hA      = (float*)(ws + 789504);          //  131072 -> 920576
  float*     hB      = (float*)(ws + 920576);          //  131072 -> 1051648
  int*       resT    = (int*)(ws + 1051648);           //  524288 -> 1575936
  unsigned*  rowsegs = (unsigned*)(ws + 1575936);      //  524288 -> 2100224
  unsigned*  rowcnt  = (unsigned*)(ws + 2100224);      //     512 -> 2100736
  unsigned*  lhist   = (unsigned*)(ws + 2100736);      //  524800 -> 2625536
  unsigned*  rowoff  = (unsigned*)(ws + 2625536);      //  524800 -> 3150336
  unsigned*  cursors = (unsigned*)(ws + 3150336);      //    4100 -> 3154560 (pad)
  unsigned*  Warr    = (unsigned*)(ws + 3154560);      //    4100 -> 3158784 (pad)
  unsigned*  nseg    = (unsigned*)(ws + 3158784);      //       4 -> 3158912 (pad)
  unsigned*  segs    = (unsigned*)(ws + 3158912);      //  524288 -> 3683200
  unsigned*  sstart  = (unsigned*)(ws + 3683200);      //   65536 -> 3748736
  unsigned*  preexS  = (unsigned*)(ws + 3748736);      //   65536 -> 3814272
  const size_t gi_off = 3814400;                       // 256B aligned

  // gi (CH*128*768 f16) + A16 (CH*128*256 f16) both after gi_off
  int CH = T_DIM;
  while (CH > 256) {
    size_t need = gi_off + (size_t)CH * 128 * (N3 + H_DIM) * 2;
    if (need <= ws_size) break;
    CH >>= 1;
  }
  _Float16* gibuf = (_Float16*)(ws + gi_off);
  _Float16* A16   = (_Float16*)(ws + gi_off + (size_t)CH * 128 * N3 * 2);

  prep_whb<<<384, 256, 0, stream>>>(Wh, WhB);
  prep_witp<<<768, 256, 0, stream>>>(Wi, WiTp);
  prep_bip<<<1, 768, 0, stream>>>(bi, bip);
  init_h<<<128, 256, 0, stream>>>(h0, hA);
  seg_transpose<<<512, 256, 0, stream>>>(resets, resT);

  float* hbufs[2] = {hA, hB};
  for (int c = 0, t0 = 0; t0 < T_DIM; ++c, t0 += CH) {
    int steps = (t0 + CH <= T_DIM) ? CH : (T_DIM - t0);
    int M = steps * B_DIM;
    int Q = (M + NSTREAM - 1) / NSTREAM;   // equal-work quantum (32 @ CH=1024)
    if (Q < 1) Q = 1;

    conv_a<<<2048, 256, 0, stream>>>(ins + (size_t)t0 * B_DIM * H_DIM, A16, M * 32);

    dim3 ggrid(N3 / 128, M / 128);
    gi_gemm<<<ggrid, 256, 0, stream>>>(A16, WiTp, bip, gibuf, M);

    seg_extract<<<128, 256, 0, stream>>>(resT, t0, steps, rowsegs, rowcnt, lhist);
    seg_prefix2<<<1, 1024, 0, stream>>>(lhist, rowoff, cursors, Warr, nseg, steps);
    seg_scatter2<<<512, 256, 0, stream>>>(rowsegs, rowcnt, rowoff, cursors, segs);
    hipMemsetAsync(sstart, 0xFF, 131072, stream);   // sstart + preexS
    str_mark<<<512, 256, 0, stream>>>(segs, nseg, cursors, Warr, sstart, preexS, Q);

    scan_stream<<<NSTREAM / ROWS, 512, 0, stream>>>(
        (const _Float16*)WhB, gibuf, segs, sstart, preexS, nseg, bhn,
        hbufs[c & 1], hbufs[(c + 1) & 1], ys, hfin, t0, steps, Q);
  }
}